// Round 1
// baseline (134.294 us; speedup 1.0000x reference)
//
#include <hip/hip_runtime.h>

// FusedSOSCascade: 8-section biquad cascade, C=128 channels, T=65536 samples.
// Strategy: overlap-and-discard chunking. Chunk L=128 with warm-up W=512.
// Poles r<=0.95 -> 0.95^512 ~ 4e-12 decay: warm-up truncation error negligible.
// Each 64-thread block covers 64 chunks (8192 samples) of one channel,
// staged in LDS (+512 halo) with +1-per-128 padding (stride 129 -> 2-way
// bank aliasing, free on gfx950).

#define C_CH   128
#define T_LEN  65536
#define L_CHK  128            // chunk length (output samples per thread)
#define W_WARM 512            // warm-up samples per thread (4 segments of 128)
#define CPB    64             // chunks per block == threads per block
#define SPAN   (CPB * L_CHK)  // 8192 samples per block
#define LDS_RAW (W_WARM + SPAN)             // 8704 floats
#define LDS_PAD (LDS_RAW + LDS_RAW / 128)   // 8772 floats (~35 KB)

// One cascade step: s is the section input, updated in place to the output.
#define CASCADE_STEP(s)                                        \
  do {                                                         \
    _Pragma("unroll")                                          \
    for (int k = 0; k < 8; ++k) {                              \
      float acc = fmaf(b2c[k], x2s[k], b1c[k] * x1s[k]);       \
      acc = fmaf(na1c[k], y1s[k], acc);                        \
      acc = fmaf(na2c[k], y2s[k], acc);                        \
      float y = fmaf(b0c[k], (s), acc);                        \
      x2s[k] = x1s[k]; x1s[k] = (s);                           \
      y2s[k] = y1s[k]; y1s[k] = y;                             \
      (s) = y;                                                 \
    }                                                          \
  } while (0)

__global__ __launch_bounds__(64, 4)
void FusedSOSCascade_20040317403806_kernel(const float* __restrict__ x,
                                           const float* __restrict__ sos,
                                           float* __restrict__ out) {
  __shared__ float lds[LDS_PAD];

  const int tid  = threadIdx.x;          // 0..63, = chunk index within block
  const int blk  = blockIdx.x;           // 0..1023
  const int ch   = blk >> 3;             // 8 blocks per channel
  const int part = blk & 7;
  const float* xc = x + (size_t)ch * T_LEN;
  const int span0 = part * SPAN;         // first output sample of this block

  // ---- Stage global -> LDS: samples [span0 - W, span0 + SPAN), zero-filled
  // below 0 (exact rest state for the first chunks of each channel).
  // Coalesced float4 loads; padded scalar LDS writes (float4 never crosses a
  // pad boundary since m%4==0 and pads fall every 128).
#pragma unroll 1
  for (int k = 0; k < LDS_RAW / 4 / CPB; ++k) {  // 34 iterations
    const int m = (tid + k * CPB) * 4;           // 0..8700, step 256 floats/wave
    const int g = span0 - W_WARM + m;            // sample index in channel
    float4 v = make_float4(0.f, 0.f, 0.f, 0.f);
    if (g >= 0) v = *(const float4*)(xc + g);    // g<0 => whole vec below 0
    const int idx = m + (m >> 7);
    lds[idx]     = v.x;
    lds[idx + 1] = v.y;
    lds[idx + 2] = v.z;
    lds[idx + 3] = v.w;
  }
  __syncthreads();

  // ---- Coefficients (uniform; a0 == 1.0 per reference construction).
  float b0c[8], b1c[8], b2c[8], na1c[8], na2c[8];
#pragma unroll
  for (int k = 0; k < 8; ++k) {
    const float a0 = sos[k * 6 + 3];
    b0c[k]  =  sos[k * 6 + 0] / a0;
    b1c[k]  =  sos[k * 6 + 1] / a0;
    b2c[k]  =  sos[k * 6 + 2] / a0;
    na1c[k] = -(sos[k * 6 + 4] / a0);
    na2c[k] = -(sos[k * 6 + 5] / a0);
  }

  // ---- Per-section DF-I state, zero-initialized.
  float x1s[8], x2s[8], y1s[8], y2s[8];
#pragma unroll
  for (int k = 0; k < 8; ++k) { x1s[k] = x2s[k] = y1s[k] = y2s[k] = 0.f; }

  // Padded LDS index for this thread's stream: m = tid*128 + step.
  int idx = tid * 129;

  // ---- Warm-up: 4 segments of 128 steps, outputs discarded.
#pragma unroll 1
  for (int seg = 0; seg < 4; ++seg) {
#pragma unroll 4
    for (int t = 0; t < 128; ++t) {
      float s = lds[idx++];
      CASCADE_STEP(s);
    }
    idx += 1;  // pad crossing at each 128-sample boundary
  }

  // ---- Output segment: 128 steps, float4-buffered coalesced-per-thread store.
  float* op = out + (size_t)ch * T_LEN + span0 + tid * L_CHK;
#pragma unroll 1
  for (int t4 = 0; t4 < 128; t4 += 4) {
    float ys[4];
#pragma unroll
    for (int j = 0; j < 4; ++j) {
      float s = lds[idx++];
      CASCADE_STEP(s);
      ys[j] = s;
    }
    *(float4*)(op + t4) = make_float4(ys[0], ys[1], ys[2], ys[3]);
  }
}

extern "C" void kernel_launch(void* const* d_in, const int* in_sizes, int n_in,
                              void* d_out, int out_size, void* d_ws, size_t ws_size,
                              hipStream_t stream) {
  const float* x   = (const float*)d_in[0];   // [128, 65536] fp32
  const float* sos = (const float*)d_in[1];   // [8, 6] fp32
  float* out = (float*)d_out;                 // [128, 65536] fp32
  (void)in_sizes; (void)n_in; (void)out_size; (void)d_ws; (void)ws_size;

  FusedSOSCascade_20040317403806_kernel<<<dim3(1024), dim3(64), 0, stream>>>(
      x, sos, out);
}

// Round 2
// 112.467 us; speedup vs baseline: 1.1941x; 1.1941x over previous
//
#include <hip/hip_runtime.h>

// FusedSOSCascade: 8-section biquad cascade, C=128 channels, T=65536 samples.
// Overlap-and-discard: chunk L=128, warm-up W=256 (poles r<0.95 ->
// 0.95^256 ~ 2e-6 decay; truncation error << 3.5e-2 threshold).
// R2 change vs R1: Direct-Form-II-Transposed sections (5 FMA, 2 states, NO
// rotation movs -- R1's DF-I cost ~80 inst/step, half of it v_mov) and
// W 512->256 (steps/thread 640->384).
// Each 64-thread block covers 64 chunks (8192 samples) of one channel,
// staged in LDS (+256 halo), +1-float pad per 128 (read stride 129 -> 2-way
// bank aliasing, free on gfx950 per m136).

#define T_LEN  65536
#define L_CHK  128            // output samples per thread
#define W_WARM 256            // warm-up samples per thread (2 segments of 128)
#define CPB    64             // chunks per block == threads per block
#define SPAN   (CPB * L_CHK)  // 8192 samples per block
#define LDS_RAW (W_WARM + SPAN)             // 8448 floats
#define LDS_PAD (LDS_RAW + LDS_RAW / 128)   // 8514 floats (~34 KB)

// One cascade step, DF2T. s: section input, updated in place to the output.
#define CASCADE_STEP(s)                                        \
  do {                                                         \
    _Pragma("unroll")                                          \
    for (int k = 0; k < 8; ++k) {                              \
      float y  = fmaf(b0c[k], (s), z1s[k]);                    \
      z1s[k]   = fmaf(b1c[k], (s), fmaf(na1c[k], y, z2s[k]));  \
      z2s[k]   = fmaf(b2c[k], (s), na2c[k] * y);               \
      (s) = y;                                                 \
    }                                                          \
  } while (0)

__global__ __launch_bounds__(64)
void FusedSOSCascade_20040317403806_kernel(const float* __restrict__ x,
                                           const float* __restrict__ sos,
                                           float* __restrict__ out) {
  __shared__ float lds[LDS_PAD];

  const int tid  = threadIdx.x;          // 0..63, = chunk index within block
  const int blk  = blockIdx.x;           // 0..1023
  const int ch   = blk >> 3;             // 8 blocks per channel
  const int part = blk & 7;
  const float* xc = x + (size_t)ch * T_LEN;
  const int span0 = part * SPAN;         // first output sample of this block

  // ---- Stage global -> LDS: samples [span0 - W, span0 + SPAN), zero-filled
  // below 0 (exact rest state for the first chunks of each channel).
  // Coalesced float4 loads; padded scalar LDS writes (a float4 never crosses
  // a pad boundary: m%4==0, pads fall every 128).
#pragma unroll 1
  for (int k = 0; k < LDS_RAW / 4 / CPB; ++k) {  // 33 iterations
    const int m = (tid + k * CPB) * 4;           // step 256 floats per wave
    const int g = span0 - W_WARM + m;            // sample index in channel
    float4 v = make_float4(0.f, 0.f, 0.f, 0.f);
    if (g >= 0) v = *(const float4*)(xc + g);    // g<0 => whole vec below 0
    const int idx = m + (m >> 7);
    lds[idx]     = v.x;
    lds[idx + 1] = v.y;
    lds[idx + 2] = v.z;
    lds[idx + 3] = v.w;
  }
  __syncthreads();

  // ---- Coefficients (wave-uniform -> SGPRs; a0 == 1.0 per construction).
  float b0c[8], b1c[8], b2c[8], na1c[8], na2c[8];
#pragma unroll
  for (int k = 0; k < 8; ++k) {
    const float a0 = sos[k * 6 + 3];
    b0c[k]  =  sos[k * 6 + 0] / a0;
    b1c[k]  =  sos[k * 6 + 1] / a0;
    b2c[k]  =  sos[k * 6 + 2] / a0;
    na1c[k] = -(sos[k * 6 + 4] / a0);
    na2c[k] = -(sos[k * 6 + 5] / a0);
  }

  // ---- DF2T state, zero-initialized (filter at rest).
  float z1s[8], z2s[8];
#pragma unroll
  for (int k = 0; k < 8; ++k) { z1s[k] = z2s[k] = 0.f; }

  // Padded LDS index of this thread's stream: raw m = tid*128 + step.
  int idx = tid * 129;

  // ---- Warm-up: 2 segments of 128 steps, outputs discarded.
#pragma unroll 1
  for (int seg = 0; seg < 2; ++seg) {
#pragma unroll 8
    for (int t = 0; t < 128; ++t) {
      float s = lds[idx++];
      CASCADE_STEP(s);
    }
    idx += 1;  // pad crossing at each 128-sample boundary
  }

  // ---- Output segment: 128 steps, float4-buffered stores.
  float* op = out + (size_t)ch * T_LEN + span0 + tid * L_CHK;
#pragma unroll 1
  for (int t4 = 0; t4 < 128; t4 += 4) {
    float ys[4];
#pragma unroll
    for (int j = 0; j < 4; ++j) {
      float s = lds[idx++];
      CASCADE_STEP(s);
      ys[j] = s;
    }
    *(float4*)(op + t4) = make_float4(ys[0], ys[1], ys[2], ys[3]);
  }
}

extern "C" void kernel_launch(void* const* d_in, const int* in_sizes, int n_in,
                              void* d_out, int out_size, void* d_ws, size_t ws_size,
                              hipStream_t stream) {
  const float* x   = (const float*)d_in[0];   // [128, 65536] fp32
  const float* sos = (const float*)d_in[1];   // [8, 6] fp32
  float* out = (float*)d_out;                 // [128, 65536] fp32
  (void)in_sizes; (void)n_in; (void)out_size; (void)d_ws; (void)ws_size;

  FusedSOSCascade_20040317403806_kernel<<<dim3(1024), dim3(64), 0, stream>>>(
      x, sos, out);
}

// Round 3
// 107.449 us; speedup vs baseline: 1.2498x; 1.0467x over previous
//
#include <hip/hip_runtime.h>

// FusedSOSCascade: 8-section biquad cascade (DF2T), C=128, T=65536, fp32.
// Overlap-and-discard: chunk L=128 per thread, warm-up W=192
// (max pole r<0.95 -> 0.95^192 ~ 5e-5 decay; truncation << 3.5e-2 threshold).
// 1024 blocks x 64 thr = 1024 waves = exactly 1 wave/SIMD (LDS-capped at
// 4 blocks/CU). A single wave saturates the fp32 pipe (32 FMA/cyc/SIMD)
// IF stall-free, so R3 removes the two R2 stalls:
//   1. compute: register double-buffered 8-sample ds_read groups (reads for
//      group g+1 issued before computing group g -> ~120cyc LDS latency
//      hidden under ~640 issue-cycles of FMA).
//   2. staging: 8 global_load_dwordx4 issued per batch before ds_writes
//      (R2's unroll-1 loop serialized one HBM latency per load).
// LDS pad +1 float per 128 (stride 129): read bank = (tid+t)%32 -> 2-way,
// free on gfx950 (m136). Pad crossings fall at t=128,256 uniformly for all
// threads since L==128.

#define T_LEN  65536
#define L_CHK  128                       // output samples per thread
#define W_WARM 192                       // warm-up samples per thread
#define CPB    64                        // chunks per block (= threads)
#define SPAN   (CPB * L_CHK)             // 8192 samples per block
#define LDS_RAW (W_WARM + SPAN)          // 8384 floats
#define LDS_PAD (LDS_RAW + LDS_RAW / 128 + 1)  // 8450 floats (~33.8 KB)
#define NSTEP  (W_WARM + L_CHK)          // 320 steps = 40 groups of 8
#define OUTG   (W_WARM / 8)              // first output group = 24

// One DF2T cascade step: s = section input, updated in place to output.
#define CASCADE_STEP(s)                                        \
  do {                                                         \
    _Pragma("unroll")                                          \
    for (int k = 0; k < 8; ++k) {                              \
      float y  = fmaf(b0c[k], (s), z1s[k]);                    \
      z1s[k]   = fmaf(b1c[k], (s), fmaf(na1c[k], y, z2s[k]));  \
      z2s[k]   = fmaf(b2c[k], (s), na2c[k] * y);               \
      (s) = y;                                                 \
    }                                                          \
  } while (0)

// Load 8 samples of group `grp` (steps t=8*grp..8*grp+7) into buf[8].
// Padded index of step t: idx0 + t + (t>>7); for j<8, (8g+j)>>7 == (8g)>>7.
#define LOADGRP(buf, grp)                                      \
  do {                                                         \
    const int gb = idx0 + 8 * (grp) + ((grp) >> 4);            \
    _Pragma("unroll")                                          \
    for (int j = 0; j < 8; ++j) (buf)[j] = lds[gb + j];        \
  } while (0)

// Run 8 cascade steps from buf; groups >= OUTG store 8 outputs (two float4).
#define STEPGRP(buf, grp)                                      \
  do {                                                         \
    float ys[8];                                               \
    _Pragma("unroll")                                          \
    for (int j = 0; j < 8; ++j) {                              \
      float s = (buf)[j];                                      \
      CASCADE_STEP(s);                                         \
      ys[j] = s;                                               \
    }                                                          \
    if ((grp) >= OUTG) {                                       \
      const int o = 8 * ((grp) - OUTG);                        \
      *(float4*)(op + o)     = make_float4(ys[0], ys[1], ys[2], ys[3]); \
      *(float4*)(op + o + 4) = make_float4(ys[4], ys[5], ys[6], ys[7]); \
    }                                                          \
  } while (0)

__global__ __launch_bounds__(64)
void FusedSOSCascade_20040317403806_kernel(const float* __restrict__ x,
                                           const float* __restrict__ sos,
                                           float* __restrict__ out) {
  __shared__ float lds[LDS_PAD];

  const int tid  = threadIdx.x;          // 0..63
  const int blk  = blockIdx.x;           // 0..1023
  const int ch   = blk >> 3;             // 8 blocks per channel
  const int part = blk & 7;
  const float* xc = x + (size_t)ch * T_LEN;
  const int span0 = part * SPAN;

  // ---- Stage global -> LDS, batched 8 loads at a time so 8 HBM requests
  // are in flight before the first ds_write's waitcnt.
#pragma unroll 1
  for (int k0 = 0; k0 < 40; k0 += 8) {
    float4 v[8];
#pragma unroll
    for (int j = 0; j < 8; ++j) {
      const int m = (tid + ((k0 + j) << 6)) << 2;   // float index, %4==0
      const int g = span0 - W_WARM + m;
      float4 t = make_float4(0.f, 0.f, 0.f, 0.f);
      if (m < LDS_RAW && g >= 0) t = *(const float4*)(xc + g);
      v[j] = t;
    }
#pragma unroll
    for (int j = 0; j < 8; ++j) {
      const int m = (tid + ((k0 + j) << 6)) << 2;
      if (m < LDS_RAW) {
        const int id = m + (m >> 7);   // pads every 128 floats; m%4==0 so a
        lds[id]     = v[j].x;          // float4 never straddles a pad
        lds[id + 1] = v[j].y;
        lds[id + 2] = v[j].z;
        lds[id + 3] = v[j].w;
      }
    }
  }
  __syncthreads();

  // ---- Coefficients (a0 == 1.0 by construction; divide anyway).
  float b0c[8], b1c[8], b2c[8], na1c[8], na2c[8];
#pragma unroll
  for (int k = 0; k < 8; ++k) {
    const float a0 = sos[k * 6 + 3];
    b0c[k]  =  sos[k * 6 + 0] / a0;
    b1c[k]  =  sos[k * 6 + 1] / a0;
    b2c[k]  =  sos[k * 6 + 2] / a0;
    na1c[k] = -(sos[k * 6 + 4] / a0);
    na2c[k] = -(sos[k * 6 + 5] / a0);
  }

  // ---- DF2T state at rest.
  float z1s[8], z2s[8];
#pragma unroll
  for (int k = 0; k < 8; ++k) { z1s[k] = z2s[k] = 0.f; }

  const int idx0 = tid * 129;            // padded base of this thread's stream
  float* op = out + (size_t)ch * T_LEN + span0 + tid * L_CHK;

  // ---- 40 groups of 8 steps, software-pipelined: load g+1 before compute g.
  float buf0[8], buf1[8];
  LOADGRP(buf0, 0);
#pragma unroll 1
  for (int gp = 0; gp < 19; ++gp) {
    const int gA = 2 * gp;
    LOADGRP(buf1, gA + 1);
    STEPGRP(buf0, gA);
    LOADGRP(buf0, gA + 2);
    STEPGRP(buf1, gA + 1);
  }
  LOADGRP(buf1, 39);
  STEPGRP(buf0, 38);
  STEPGRP(buf1, 39);
}

extern "C" void kernel_launch(void* const* d_in, const int* in_sizes, int n_in,
                              void* d_out, int out_size, void* d_ws, size_t ws_size,
                              hipStream_t stream) {
  const float* x   = (const float*)d_in[0];   // [128, 65536] fp32
  const float* sos = (const float*)d_in[1];   // [8, 6] fp32
  float* out = (float*)d_out;                 // [128, 65536] fp32
  (void)in_sizes; (void)n_in; (void)out_size; (void)d_ws; (void)ws_size;

  FusedSOSCascade_20040317403806_kernel<<<dim3(1024), dim3(64), 0, stream>>>(
      x, sos, out);
}